// Round 4
// baseline (1449.330 us; speedup 1.0000x reference)
//
#include <hip/hip_runtime.h>
#include <cstdint>
#include <cstddef>

#define B_     16
#define T_     128
#define J_     24
#define H_     256
#define HEADS_ 8
#define DH_    32
#define L_     4
#define RANK_  8
#define M_     12
#define NTOK   (B_*T_)       // 2048
#define ROWS   (NTOK*J_)     // 49152
#define KQ     320           // fused QKV K: 256 h + 8 lora-R + 56 zero pad
#define HAS_G_MASK 3821      // bit m set iff NUM_GLOBAL_LIST[m] > 0

typedef __attribute__((ext_vector_type(8))) short short8;
typedef __attribute__((ext_vector_type(4))) float f32x4;

__constant__ int cNJ[M_] = {8, 10, 12, 14, 16, 18, 20, 22, 24, 9, 13, 17};

__device__ __forceinline__ float bf2f(unsigned short u) {
    union { unsigned int i; float f; } c; c.i = ((unsigned int)u) << 16; return c.f;
}
__device__ __forceinline__ unsigned short f2bf(float f) {
    union { float f; unsigned int i; } c; c.f = f;
    unsigned int x = c.i;
    return (unsigned short)((x + 0x7fffu + ((x >> 16) & 1u)) >> 16);
}
__device__ __forceinline__ float asf(unsigned int u) {
    union { unsigned int i; float f; } c; c.i = u; return c.f;
}
// packed f32x2 -> bf16x2 (RNE, matches f2bf)
__device__ __forceinline__ unsigned int cvtpk(float lo, float hi) {
    unsigned int r;
    asm("v_cvt_pk_bf16_f32 %0, %1, %2" : "=v"(r) : "v"(lo), "v"(hi));
    return r;
}
__device__ __forceinline__ void gload16(const void* g, void* l) {
    __builtin_amdgcn_global_load_lds((const __attribute__((address_space(1))) void*)g,
                                     (__attribute__((address_space(3))) void*)l, 16, 0, 0);
}

// ---------------------------------------------------------------- mask dtype probe
__global__ void zero_flag(int* f) { *f = 0; }

__global__ __launch_bounds__(256) void detect_kernel(
    const unsigned char* __restrict__ sl, const unsigned char* __restrict__ hi,
    const unsigned char* __restrict__ gl, const int* __restrict__ m_idx,
    int* __restrict__ flag) {
    int rj = blockIdx.x * 256 + threadIdx.x;
    if (rj >= ROWS) return;
    int b = rj / (T_ * J_);
    int j = rj % J_;
    int valid = (j < cNJ[m_idx[b]]) ? 1 : 0;
    int cnt = (sl[rj] != 0) + (hi[rj] != 0) + (gl[rj] != 0);
    if (cnt != valid) atomicOr(flag, 1);
}

// ---------------------------------------------------------------- weights f32 -> bf16 transposed
// src: [L][K][Nc] f32 -> dst: [L][Nc][K] bf16.  Coalesced WRITES (strided reads hit L2/L3).
__global__ void wconv_t(const float* __restrict__ W, unsigned short* __restrict__ WT,
                        int K, int Nc, int total) {
    int i = blockIdx.x * 256 + threadIdx.x;
    if (i >= total) return;
    int kn = K * Nc;
    int l = i / kn;
    int r = i - l * kn;
    int n = r / K;
    int k = r - n * K;
    WT[i] = f2bf(W[(size_t)l * kn + (size_t)k * Nc + n]);
}

// fused QKV B': [L][M][768][KQ] bf16 = [Wqkv^T ; loraB^T ; zeros]
__global__ void wconv_qkv(const float* __restrict__ Wqkv, const float* __restrict__ loraB,
                          unsigned short* __restrict__ OT) {
    int i = blockIdx.x * 256 + threadIdx.x;
    const int total = L_ * M_ * 768 * KQ;
    if (i >= total) return;
    int k = i % KQ;
    int n = (i / KQ) % 768;
    int m = (i / (KQ * 768)) % M_;
    int l = i / (KQ * 768 * M_);
    float v = 0.f;
    if (k < 256)      v = Wqkv[((size_t)l * 256 + k) * 768 + n];
    else if (k < 264) v = loraB[(((size_t)l * M_ + m) * RANK_ + (k - 256)) * 768 + n];
    OT[i] = f2bf(v);
}

// ---------------------------------------------------------------- embedding (wave per row)
__global__ __launch_bounds__(256) void embed_kernel(
    const float* __restrict__ act, const void* __restrict__ slide,
    const void* __restrict__ hinge, const void* __restrict__ glob,
    const int* __restrict__ m_idx, const int* __restrict__ flag,
    const float* __restrict__ Ws, const float* __restrict__ bs,
    const float* __restrict__ Wh, const float* __restrict__ bh,
    const float* __restrict__ Wg, const float* __restrict__ Wact,
    const float* __restrict__ pos, float* __restrict__ X) {
    int rj = (blockIdx.x << 2) + (threadIdx.x >> 6);
    int lane = threadIdx.x & 63;
    int b = rj / (T_ * J_);
    int j = rj % J_;
    int m = m_idx[b];
    bool valid = j < cNJ[m];
    bool s, hh, gl;
    if (*flag) {
        s  = ((const int*)slide)[rj] != 0;
        hh = ((const int*)hinge)[rj] != 0;
        gl = ((const int*)glob)[rj]  != 0;
    } else {
        s  = ((const unsigned char*)slide)[rj] != 0;
        hh = ((const unsigned char*)hinge)[rj] != 0;
        gl = ((const unsigned char*)glob)[rj]  != 0;
    }
    float a1 = act[rj];
    int h0 = lane << 2;
    float e0 = 0.f, e1 = 0.f, e2 = 0.f, e3 = 0.f;
    if (s) {
        float4 w = *(const float4*)(Ws + h0); float4 bb = *(const float4*)(bs + h0);
        e0 = a1 * w.x + bb.x; e1 = a1 * w.y + bb.y; e2 = a1 * w.z + bb.z; e3 = a1 * w.w + bb.w;
    } else if (hh) {
        float4 w = *(const float4*)(Wh + h0); float4 bb = *(const float4*)(bh + h0);
        e0 = a1 * w.x + bb.x; e1 = a1 * w.y + bb.y; e2 = a1 * w.z + bb.z; e3 = a1 * w.w + bb.w;
    } else if (gl && ((HAS_G_MASK >> m) & 1)) {
        float4 w = *(const float4*)(Wg + m * H_ + h0);
        e0 = a1 * w.x; e1 = a1 * w.y; e2 = a1 * w.z; e3 = a1 * w.w;
    }
    if (valid) {
        float4 wa = *(const float4*)(Wact + h0);
        e0 += wa.x; e1 += wa.y; e2 += wa.z; e3 += wa.w;
    }
    float4 pv = *(const float4*)(pos + (size_t)(m * J_ + j) * H_ + h0);
    float4 out; out.x = e0 + pv.x; out.y = e1 + pv.y; out.z = e2 + pv.z; out.w = e3 + pv.w;
    *(float4*)(X + ((size_t)rj << 8) + h0) = out;
}

// ---------------------------------------------------------------- LayerNorm (+ optional LoRA-A tail), wave per row
// LORA: output rows are KQ(320) wide: [hn(256) | R(8 bf16) | zeros(56)]
template<bool LORA>
__global__ __launch_bounds__(256) void ln_kernel(
    const float* __restrict__ X, const float* __restrict__ sc, const float* __restrict__ bi,
    const float* __restrict__ lA, const int* __restrict__ m_idx,
    unsigned short* __restrict__ Hbf, int ldh) {
    int row = (blockIdx.x << 2) + (threadIdx.x >> 6);
    int lane = threadIdx.x & 63;
    int h0 = lane << 2;
    float4 xv = *(const float4*)(X + ((size_t)row << 8) + h0);
    float s1 = xv.x + xv.y + xv.z + xv.w;
    float s2 = xv.x * xv.x + xv.y * xv.y + xv.z * xv.z + xv.w * xv.w;
    #pragma unroll
    for (int o = 32; o; o >>= 1) { s1 += __shfl_xor(s1, o); s2 += __shfl_xor(s2, o); }
    float mu = s1 * (1.f / H_);
    float var = s2 * (1.f / H_) - mu * mu;
    float rs = rsqrtf(var + 1e-5f);
    float4 scv = *(const float4*)(sc + h0);
    float4 biv = *(const float4*)(bi + h0);
    float hn0 = (xv.x - mu) * rs * scv.x + biv.x;
    float hn1 = (xv.y - mu) * rs * scv.y + biv.y;
    float hn2 = (xv.z - mu) * rs * scv.z + biv.z;
    float hn3 = (xv.w - mu) * rs * scv.w + biv.w;
    ushort4 o4; o4.x = f2bf(hn0); o4.y = f2bf(hn1); o4.z = f2bf(hn2); o4.w = f2bf(hn3);
    *(ushort4*)(Hbf + (size_t)row * ldh + h0) = o4;
    if (LORA) {
        int t = m_idx[row / (J_ * T_)];
        const float* Ap = lA + (size_t)t * (H_ * RANK_) + h0 * RANK_;
        float4 av[8];
        #pragma unroll
        for (int c = 0; c < 8; ++c) av[c] = ((const float4*)Ap)[c];
        float hn[4] = {hn0, hn1, hn2, hn3};
        float p[RANK_];
        #pragma unroll
        for (int k = 0; k < RANK_; ++k) p[k] = 0.f;
        #pragma unroll
        for (int i = 0; i < 4; ++i)
            #pragma unroll
            for (int k = 0; k < RANK_; ++k) {
                int idx = i * RANK_ + k;
                float a = (idx & 3) == 0 ? av[idx >> 2].x : (idx & 3) == 1 ? av[idx >> 2].y
                        : (idx & 3) == 2 ? av[idx >> 2].z : av[idx >> 2].w;
                p[k] += hn[i] * a;
            }
        #pragma unroll
        for (int k = 0; k < RANK_; ++k)
            #pragma unroll
            for (int o = 32; o; o >>= 1) p[k] += __shfl_xor(p[k], o);
        // tail: 64 elems = [R(8) | zeros(56)] as 32 u32 stores by lanes 0-31
        unsigned int w0 = (unsigned int)f2bf(p[0]) | ((unsigned int)f2bf(p[1]) << 16);
        unsigned int w1 = (unsigned int)f2bf(p[2]) | ((unsigned int)f2bf(p[3]) << 16);
        unsigned int w2 = (unsigned int)f2bf(p[4]) | ((unsigned int)f2bf(p[5]) << 16);
        unsigned int w3 = (unsigned int)f2bf(p[6]) | ((unsigned int)f2bf(p[7]) << 16);
        unsigned int tv = 0;
        if (lane == 0) tv = w0; else if (lane == 1) tv = w1;
        else if (lane == 2) tv = w2; else if (lane == 3) tv = w3;
        if (lane < 32)
            *((unsigned int*)(Hbf + (size_t)row * ldh + 256) + lane) = tv;
    }
}

// ---------------------------------------------------------------- final LayerNorm (in place, wave per row)
__global__ __launch_bounds__(256) void lnf_kernel(
    float* __restrict__ X, const float* __restrict__ sc, const float* __restrict__ bi) {
    int row = (blockIdx.x << 2) + (threadIdx.x >> 6);
    int lane = threadIdx.x & 63;
    int h0 = lane << 2;
    float4 xv = *(const float4*)(X + ((size_t)row << 8) + h0);
    float s1 = xv.x + xv.y + xv.z + xv.w;
    float s2 = xv.x * xv.x + xv.y * xv.y + xv.z * xv.z + xv.w * xv.w;
    #pragma unroll
    for (int o = 32; o; o >>= 1) { s1 += __shfl_xor(s1, o); s2 += __shfl_xor(s2, o); }
    float mu = s1 * (1.f / H_);
    float var = s2 * (1.f / H_) - mu * mu;
    float rs = rsqrtf(var + 1e-5f);
    float4 scv = *(const float4*)(sc + h0);
    float4 biv = *(const float4*)(bi + h0);
    float4 out;
    out.x = (xv.x - mu) * rs * scv.x + biv.x;
    out.y = (xv.y - mu) * rs * scv.y + biv.y;
    out.z = (xv.z - mu) * rs * scv.z + biv.z;
    out.w = (xv.w - mu) * rs * scv.w + biv.w;
    *(float4*)(X + ((size_t)row << 8) + h0) = out;
}

// ---------------------------------------------------------------- GEMM: C = A[ROWSxK] @ B[KxNc] (+epilogue)
// A bf16 row-major (lda=K). BT bf16 = B^T (Nc x K) row-major.
// EPI 0: QKV  (bias, store bf16 ld=768; BT indexed by block-uniform model type)
// EPI 1: GELU (bias + gelu, store bf16 ld=Nc)
// EPI 2: RESID(bias, X += g*val, f32 ld=256)
template<int EPI>
__global__ __launch_bounds__(256) void gemm_k(
    const unsigned short* __restrict__ A, const unsigned short* __restrict__ BT,
    const float* __restrict__ bias,
    const float* __restrict__ aux1,   // RESID: gvec
    const int* __restrict__ m_idx,
    unsigned short* __restrict__ outB, float* __restrict__ outF,
    int K, int Nc) {
    __shared__ __align__(16) unsigned short As[128 * 64];
    __shared__ __align__(16) unsigned short Bs[128 * 64];
    int gx = gridDim.x;
    int nwg = gx * gridDim.y;
    int id = blockIdx.y * gx + blockIdx.x;
    int bx = blockIdx.x, by = blockIdx.y;
    if ((nwg & 7) == 0) {
        int q8 = nwg >> 3;
        int sid = (id & 7) * q8 + (id >> 3);
        bx = sid % gx; by = sid / gx;
    }
    int col0 = bx * 128;
    int row0 = by * 128;
    int tid = threadIdx.x;
    int wv = tid >> 6, lane = tid & 63;
    int wm = wv >> 1, wn = wv & 1;

    if (EPI == 0) BT += (size_t)m_idx[row0 / (J_ * T_)] * (768 * KQ);

    f32x4 acc[4][4];
    const f32x4 z = {0.f, 0.f, 0.f, 0.f};
    #pragma unroll
    for (int mi = 0; mi < 4; ++mi)
        #pragma unroll
        for (int ni = 0; ni < 4; ++ni) acc[mi][ni] = z;

    for (int k0 = 0; k0 < K; k0 += 64) {
        #pragma unroll
        for (int it = 0; it < 4; ++it) {
            int f = (tid << 4) + (it << 12);
            int r = f >> 7;
            int ce = (f & 127) >> 1;
            gload16(A  + (size_t)(row0 + r) * K + k0 + ce, (char*)As + f);
            gload16(BT + (size_t)(col0 + r) * K + k0 + ce, (char*)Bs + f);
        }
        __syncthreads();
        #pragma unroll
        for (int kk = 0; kk < 64; kk += 32) {
            short8 af[4], bfr[4];
            int ko = kk + ((lane >> 4) << 3);
            #pragma unroll
            for (int q = 0; q < 4; ++q) {
                af[q]  = *(const short8*)(As + ((wm * 64 + q * 16 + (lane & 15)) << 6) + ko);
                bfr[q] = *(const short8*)(Bs + ((wn * 64 + q * 16 + (lane & 15)) << 6) + ko);
            }
            #pragma unroll
            for (int mi = 0; mi < 4; ++mi)
                #pragma unroll
                for (int ni = 0; ni < 4; ++ni)
                    acc[mi][ni] = __builtin_amdgcn_mfma_f32_16x16x32_bf16(af[mi], bfr[ni], acc[mi][ni], 0, 0, 0);
        }
        __syncthreads();
    }

    int rbase = row0 + wm * 64 + ((lane >> 4) << 2);
    int cbase = col0 + wn * 64 + (lane & 15);

    if (EPI == 0 || EPI == 1) {
        const int ld = (EPI == 0) ? 768 : Nc;
        bool oddl = (lane & 1);
        int colp = cbase - (oddl ? 1 : 0);       // even col of the pair
        #pragma unroll
        for (int ni = 0; ni < 4; ++ni) {
            float bv = bias[cbase + ni * 16];
            #pragma unroll
            for (int mi = 0; mi < 4; ++mi) {
                float v[4], y[4];
                #pragma unroll
                for (int r = 0; r < 4; ++r) {
                    float u = acc[mi][ni][r] + bv;
                    if (EPI == 1) {
                        float t = u * u;
                        float p = fmaf(t, 0.044715f, 1.0f) * u;
                        float e = __expf(-1.5957691216057308f * p);
                        u = u / (1.f + e);
                    }
                    v[r] = u;
                }
                #pragma unroll
                for (int r = 0; r < 4; ++r) y[r] = __shfl_xor(v[r], 1);
                // even lane packs rows 0,1 ; odd lane packs rows 2,3 (its col is the odd one)
                float f0 = oddl ? y[2] : v[0];
                float s0 = oddl ? v[2] : y[0];
                float f1 = oddl ? y[3] : v[1];
                float s1 = oddl ? v[3] : y[1];
                unsigned int p0 = cvtpk(f0, s0);
                unsigned int p1 = cvtpk(f1, s1);
                int rr = rbase + mi * 16 + (oddl ? 2 : 0);
                *(unsigned int*)(outB + (size_t)rr * ld + colp + ni * 16) = p0;
                *(unsigned int*)(outB + (size_t)(rr + 1) * ld + colp + ni * 16) = p1;
            }
        }
    } else {
        #pragma unroll
        for (int mi = 0; mi < 4; ++mi)
            #pragma unroll
            for (int r = 0; r < 4; ++r) {
                int row = rbase + mi * 16 + r;
                #pragma unroll
                for (int ni = 0; ni < 4; ++ni) {
                    int col = cbase + ni * 16;
                    float u = acc[mi][ni][r] + bias[col];
                    outF[(size_t)row * H_ + col] += aux1[col] * u;
                }
            }
    }
}

// ---------------------------------------------------------------- attention: 4 waves = 4 heads, no syncthreads
__global__ __launch_bounds__(256) void attn_kernel(
    const unsigned short* __restrict__ QKV, const int* __restrict__ m_idx,
    unsigned short* __restrict__ O) {
    __shared__ unsigned int q2s[4][24][18];
    __shared__ unsigned int k2s[4][16][26];
    __shared__ unsigned int v2s[4][24][18];
    __shared__ float       scs[4][24][27];
    int w = threadIdx.x >> 6, lane = threadIdx.x & 63;
    int n = blockIdx.x >> 1;
    int hd = ((blockIdx.x & 1) << 2) + w;
    int nj = cNJ[m_idx[n >> 7]];
    unsigned int (*q2)[18] = q2s[w];
    unsigned int (*k2)[26] = k2s[w];
    unsigned int (*v2)[18] = v2s[w];
    float (*sc)[27] = scs[w];

    const unsigned short* base = QKV + (size_t)n * (J_ * 768) + hd * DH_;

    #pragma unroll
    for (int it = 0; it < 3; ++it) {
        int r = it * 64 + lane;
        int j = r >> 3, d0 = (r & 7) << 2, d2 = d0 >> 1;
        ushort4 x = *(const ushort4*)(base + (size_t)j * 768 + d0);
        q2[j][d2]     = (unsigned int)x.x | ((unsigned int)x.y << 16);
        q2[j][d2 + 1] = (unsigned int)x.z | ((unsigned int)x.w << 16);
    }
    #pragma unroll
    for (int it = 0; it < 3; ++it) {
        int r = it * 64 + lane;
        int j = r >> 3, d0 = (r & 7) << 2, d2 = d0 >> 1;
        ushort4 x = *(const ushort4*)(base + (size_t)j * 768 + 256 + d0);
        k2[d2][j]     = (unsigned int)x.x | ((unsigned int)x.y << 16);
        k2[d2 + 1][j] = (unsigned int)x.z | ((unsigned int)x.w << 16);
    }
    #pragma unroll
    for (int it = 0; it < 3; ++it) {
        int r = it * 64 + lane;
        int j = r >> 3, d0 = (r & 7) << 2, d2 = d0 >> 1;
        ushort4 x = *(const ushort4*)(base + (size_t)j * 768 + 512 + d0);
        v2[j][d2]     = (unsigned int)x.x | ((unsigned int)x.y << 16);
        v2[j][d2 + 1] = (unsigned int)x.z | ((unsigned int)x.w << 16);
    }

    int i = lane >> 1, half = lane & 1;
    if (lane < 48) {
        float qf[32];
        #pragma unroll
        for (int d2 = 0; d2 < 16; ++d2) {
            unsigned int x = q2[i][d2];
            qf[2 * d2]     = asf(x << 16);
            qf[2 * d2 + 1] = asf(x & 0xffff0000u);
        }
        int jb = half * 12;
        float s[12];
        #pragma unroll
        for (int jj = 0; jj < 12; ++jj) {
            int j = jb + jj;
            float acc = 0.f;
            #pragma unroll
            for (int d2 = 0; d2 < 16; ++d2) {
                unsigned int x = k2[d2][j];
                acc += qf[2 * d2] * asf(x << 16);
                acc += qf[2 * d2 + 1] * asf(x & 0xffff0000u);
            }
            bool ok = (i < nj && j < nj) || (i == j);
            s[jj] = ok ? acc * 0.17677669529663687f : -1e30f;
        }
        float mx = s[0];
        #pragma unroll
        for (int jj = 1; jj < 12; ++jj) mx = fmaxf(mx, s[jj]);
        mx = fmaxf(mx, __shfl_xor(mx, 1));
        float sm = 0.f;
        #pragma unroll
        for (int jj = 0; jj < 12; ++jj) { float e = __expf(s[jj] - mx); s[jj] = e; sm += e; }
        sm += __shfl_xor(sm, 1);
        float inv = 1.f / sm;
        #pragma unroll
        for (int jj = 0; jj < 12; ++jj) sc[i][jb + jj] = s[jj] * inv;
    }

    #pragma unroll
    for (int it = 0; it < 6; ++it) {
        int i2 = it * 4 + (lane >> 4), d2 = lane & 15;
        float olo = 0.f, ohi = 0.f;
        #pragma unroll
        for (int j = 0; j < J_; ++j) {
            float p = sc[i2][j];
            unsigned int x = v2[j][d2];
            olo += p * asf(x << 16);
            ohi += p * asf(x & 0xffff0000u);
        }
        unsigned int o = (unsigned int)f2bf(olo) | ((unsigned int)f2bf(ohi) << 16);
        *(unsigned int*)(O + (size_t)(n * J_ + i2) * H_ + hd * DH_ + 2 * d2) = o;
    }
}

// ---------------------------------------------------------------- host
extern "C" void kernel_launch(void* const* d_in, const int* in_sizes, int n_in,
                              void* d_out, int out_size, void* d_ws, size_t ws_size,
                              hipStream_t stream) {
    (void)in_sizes; (void)n_in; (void)out_size; (void)ws_size;
    const float* act   = (const float*)d_in[0];
    const void*  slide = d_in[1];
    const void*  hinge = d_in[2];
    const void*  glob  = d_in[3];
    const int* m_idx  = (const int*)d_in[6];
    const float* Ws   = (const float*)d_in[7];
    const float* bs   = (const float*)d_in[8];
    const float* Wh   = (const float*)d_in[9];
    const float* bh   = (const float*)d_in[10];
    const float* Wg   = (const float*)d_in[11];
    const float* Wact = (const float*)d_in[12];
    const float* pos  = (const float*)d_in[13];
    const float* ln1s = (const float*)d_in[14];
    const float* ln1b = (const float*)d_in[15];
    const float* Wqkv = (const float*)d_in[16];
    const float* bqkv = (const float*)d_in[17];
    const float* loraA= (const float*)d_in[18];
    const float* loraB= (const float*)d_in[19];
    const float* Wo   = (const float*)d_in[20];
    const float* bo   = (const float*)d_in[21];
    const float* ln2s = (const float*)d_in[22];
    const float* ln2b = (const float*)d_in[23];
    const float* W1   = (const float*)d_in[24];
    const float* b1   = (const float*)d_in[25];
    const float* W2   = (const float*)d_in[26];
    const float* b2   = (const float*)d_in[27];
    const float* g1   = (const float*)d_in[28];
    const float* g2   = (const float*)d_in[29];
    const float* lnfs = (const float*)d_in[30];
    const float* lnfb = (const float*)d_in[31];

    float* X = (float*)d_out;

    size_t off = 0;
    char* ws = (char*)d_ws;
    auto nxt = [&](size_t bytes) -> char* {
        char* p = ws + off; off += (bytes + 255) & ~(size_t)255; return p;
    };
    int*            dflag  = (int*)nxt(256);
    unsigned short* Hbf    = (unsigned short*)nxt((size_t)ROWS * KQ * 2);        // 31.5 MB (320-wide; also 256-wide & Obf)
    unsigned short* QKVG   = (unsigned short*)nxt((size_t)ROWS * 1024 * 2);      // 101 MB (QKV & gelu alias)
    unsigned short* WqkvTp = (unsigned short*)nxt((size_t)L_ * M_ * 768 * KQ * 2); // 15.1 MB fused B'
    unsigned short* WoT    = (unsigned short*)nxt((size_t)L_ * H_ * H_ * 2);
    unsigned short* W1T    = (unsigned short*)nxt((size_t)L_ * H_ * 1024 * 2);
    unsigned short* W2T    = (unsigned short*)nxt((size_t)L_ * 1024 * H_ * 2);
    unsigned short* Obf    = Hbf;   // lifetimes disjoint

    zero_flag<<<1, 1, 0, stream>>>(dflag);
    detect_kernel<<<(ROWS + 255) / 256, 256, 0, stream>>>(
        (const unsigned char*)slide, (const unsigned char*)hinge,
        (const unsigned char*)glob, m_idx, dflag);

    wconv_qkv<<<(L_ * M_ * 768 * KQ + 255) / 256, 256, 0, stream>>>(Wqkv, loraB, WqkvTp);
    wconv_t<<<(L_ * H_ * H_   + 255) / 256, 256, 0, stream>>>(Wo, WoT, H_, H_,   L_ * H_ * H_);
    wconv_t<<<(L_ * H_ * 1024 + 255) / 256, 256, 0, stream>>>(W1, W1T, H_, 1024, L_ * H_ * 1024);
    wconv_t<<<(L_ * 1024 * H_ + 255) / 256, 256, 0, stream>>>(W2, W2T, 1024, H_, L_ * 1024 * H_);

    embed_kernel<<<ROWS / 4, 256, 0, stream>>>(act, slide, hinge, glob, m_idx, dflag,
                                               Ws, bs, Wh, bh, Wg, Wact, pos, X);

    for (int l = 0; l < L_; ++l) {
        ln_kernel<true><<<ROWS / 4, 256, 0, stream>>>(X, ln1s + l * H_, ln1b + l * H_,
                                                      loraA + (size_t)l * M_ * H_ * RANK_, m_idx, Hbf, KQ);
        gemm_k<0><<<dim3(6, 384), 256, 0, stream>>>(Hbf, WqkvTp + (size_t)l * M_ * 768 * KQ,
                                                    bqkv + l * 768, nullptr, m_idx,
                                                    QKVG, nullptr, KQ, 768);
        attn_kernel<<<NTOK * 2, 256, 0, stream>>>(QKVG, m_idx, Obf);
        gemm_k<2><<<dim3(2, 384), 256, 0, stream>>>(Obf, WoT + (size_t)l * H_ * H_,
                                                    bo + l * H_, g1 + l * H_, nullptr,
                                                    nullptr, X, H_, H_);
        ln_kernel<false><<<ROWS / 4, 256, 0, stream>>>(X, ln2s + l * H_, ln2b + l * H_,
                                                       nullptr, nullptr, Hbf, H_);
        gemm_k<1><<<dim3(8, 384), 256, 0, stream>>>(Hbf, W1T + (size_t)l * H_ * 1024,
                                                    b1 + l * 1024, nullptr, nullptr,
                                                    QKVG, nullptr, H_, 1024);
        gemm_k<2><<<dim3(2, 384), 256, 0, stream>>>(QKVG, W2T + (size_t)l * 1024 * H_,
                                                    b2 + l * H_, g2 + l * H_, nullptr,
                                                    nullptr, X, 1024, H_);
    }

    lnf_kernel<<<ROWS / 4, 256, 0, stream>>>(X, lnfs, lnfb);
}

// Round 5
// 1317.205 us; speedup vs baseline: 1.1003x; 1.1003x over previous
//
#include <hip/hip_runtime.h>
#include <cstdint>
#include <cstddef>

#define B_     16
#define T_     128
#define J_     24
#define H_     256
#define HEADS_ 8
#define DH_    32
#define L_     4
#define RANK_  8
#define M_     12
#define NTOK   (B_*T_)       // 2048
#define ROWS   (NTOK*J_)     // 49152
#define KQ     320           // fused QKV K: 256 h + 8 lora-R + 56 zero pad
#define HAS_G_MASK 3821      // bit m set iff NUM_GLOBAL_LIST[m] > 0

typedef __attribute__((ext_vector_type(8))) short short8;
typedef __attribute__((ext_vector_type(4))) float f32x4;

__constant__ int cNJ[M_] = {8, 10, 12, 14, 16, 18, 20, 22, 24, 9, 13, 17};

__device__ __forceinline__ float bf2f(unsigned short u) {
    union { unsigned int i; float f; } c; c.i = ((unsigned int)u) << 16; return c.f;
}
__device__ __forceinline__ unsigned short f2bf(float f) {
    union { float f; unsigned int i; } c; c.f = f;
    unsigned int x = c.i;
    return (unsigned short)((x + 0x7fffu + ((x >> 16) & 1u)) >> 16);
}
__device__ __forceinline__ float asf(unsigned int u) {
    union { unsigned int i; float f; } c; c.i = u; return c.f;
}
__device__ __forceinline__ void gload16(const void* g, void* l) {
    __builtin_amdgcn_global_load_lds((const __attribute__((address_space(1))) void*)g,
                                     (__attribute__((address_space(3))) void*)l, 16, 0, 0);
}
// LDS bank swizzle for 64B (BK=32 bf16) rows: spreads 16 same-col lanes over 8 16B slots
#define SWZ(r) ((((r) >> 1) & 3) << 4)

// ---------------------------------------------------------------- mask dtype probe
__global__ void zero_flag(int* f) { *f = 0; }

__global__ __launch_bounds__(256) void detect_kernel(
    const unsigned char* __restrict__ sl, const unsigned char* __restrict__ hi,
    const unsigned char* __restrict__ gl, const int* __restrict__ m_idx,
    int* __restrict__ flag) {
    int rj = blockIdx.x * 256 + threadIdx.x;
    if (rj >= ROWS) return;
    int b = rj / (T_ * J_);
    int j = rj % J_;
    int valid = (j < cNJ[m_idx[b]]) ? 1 : 0;
    int cnt = (sl[rj] != 0) + (hi[rj] != 0) + (gl[rj] != 0);
    if (cnt != valid) atomicOr(flag, 1);
}

// ---------------------------------------------------------------- weights f32 -> bf16 transposed
// src: [L][K][Nc] f32 -> dst: [L][Nc][K] bf16.  Coalesced WRITES.
__global__ void wconv_t(const float* __restrict__ W, unsigned short* __restrict__ WT,
                        int K, int Nc, int total) {
    int i = blockIdx.x * 256 + threadIdx.x;
    if (i >= total) return;
    int kn = K * Nc;
    int l = i / kn;
    int r = i - l * kn;
    int n = r / K;
    int k = r - n * K;
    WT[i] = f2bf(W[(size_t)l * kn + (size_t)k * Nc + n]);
}

// fused QKV B': [L][M][768][KQ] bf16 = [Wqkv^T ; loraB^T ; zeros]
__global__ void wconv_qkv(const float* __restrict__ Wqkv, const float* __restrict__ loraB,
                          unsigned short* __restrict__ OT) {
    int i = blockIdx.x * 256 + threadIdx.x;
    const int total = L_ * M_ * 768 * KQ;
    if (i >= total) return;
    int k = i % KQ;
    int n = (i / KQ) % 768;
    int m = (i / (KQ * 768)) % M_;
    int l = i / (KQ * 768 * M_);
    float v = 0.f;
    if (k < 256)      v = Wqkv[((size_t)l * 256 + k) * 768 + n];
    else if (k < 264) v = loraB[(((size_t)l * M_ + m) * RANK_ + (k - 256)) * 768 + n];
    OT[i] = f2bf(v);
}

// ---------------------------------------------------------------- embedding (wave per row)
__global__ __launch_bounds__(256) void embed_kernel(
    const float* __restrict__ act, const void* __restrict__ slide,
    const void* __restrict__ hinge, const void* __restrict__ glob,
    const int* __restrict__ m_idx, const int* __restrict__ flag,
    const float* __restrict__ Ws, const float* __restrict__ bs,
    const float* __restrict__ Wh, const float* __restrict__ bh,
    const float* __restrict__ Wg, const float* __restrict__ Wact,
    const float* __restrict__ pos, float* __restrict__ X) {
    int rj = (blockIdx.x << 2) + (threadIdx.x >> 6);
    int lane = threadIdx.x & 63;
    int b = rj / (T_ * J_);
    int j = rj % J_;
    int m = m_idx[b];
    bool valid = j < cNJ[m];
    bool s, hh, gl;
    if (*flag) {
        s  = ((const int*)slide)[rj] != 0;
        hh = ((const int*)hinge)[rj] != 0;
        gl = ((const int*)glob)[rj]  != 0;
    } else {
        s  = ((const unsigned char*)slide)[rj] != 0;
        hh = ((const unsigned char*)hinge)[rj] != 0;
        gl = ((const unsigned char*)glob)[rj]  != 0;
    }
    float a1 = act[rj];
    int h0 = lane << 2;
    float e0 = 0.f, e1 = 0.f, e2 = 0.f, e3 = 0.f;
    if (s) {
        float4 w = *(const float4*)(Ws + h0); float4 bb = *(const float4*)(bs + h0);
        e0 = a1 * w.x + bb.x; e1 = a1 * w.y + bb.y; e2 = a1 * w.z + bb.z; e3 = a1 * w.w + bb.w;
    } else if (hh) {
        float4 w = *(const float4*)(Wh + h0); float4 bb = *(const float4*)(bh + h0);
        e0 = a1 * w.x + bb.x; e1 = a1 * w.y + bb.y; e2 = a1 * w.z + bb.z; e3 = a1 * w.w + bb.w;
    } else if (gl && ((HAS_G_MASK >> m) & 1)) {
        float4 w = *(const float4*)(Wg + m * H_ + h0);
        e0 = a1 * w.x; e1 = a1 * w.y; e2 = a1 * w.z; e3 = a1 * w.w;
    }
    if (valid) {
        float4 wa = *(const float4*)(Wact + h0);
        e0 += wa.x; e1 += wa.y; e2 += wa.z; e3 += wa.w;
    }
    float4 pv = *(const float4*)(pos + (size_t)(m * J_ + j) * H_ + h0);
    float4 out; out.x = e0 + pv.x; out.y = e1 + pv.y; out.z = e2 + pv.z; out.w = e3 + pv.w;
    *(float4*)(X + ((size_t)rj << 8) + h0) = out;
}

// ---------------------------------------------------------------- LayerNorm (+ optional LoRA-A tail), wave per row
template<bool LORA>
__global__ __launch_bounds__(256) void ln_kernel(
    const float* __restrict__ X, const float* __restrict__ sc, const float* __restrict__ bi,
    const float* __restrict__ lA, const int* __restrict__ m_idx,
    unsigned short* __restrict__ Hbf, int ldh) {
    int row = (blockIdx.x << 2) + (threadIdx.x >> 6);
    int lane = threadIdx.x & 63;
    int h0 = lane << 2;
    float4 xv = *(const float4*)(X + ((size_t)row << 8) + h0);
    float s1 = xv.x + xv.y + xv.z + xv.w;
    float s2 = xv.x * xv.x + xv.y * xv.y + xv.z * xv.z + xv.w * xv.w;
    #pragma unroll
    for (int o = 32; o; o >>= 1) { s1 += __shfl_xor(s1, o); s2 += __shfl_xor(s2, o); }
    float mu = s1 * (1.f / H_);
    float var = s2 * (1.f / H_) - mu * mu;
    float rs = rsqrtf(var + 1e-5f);
    float4 scv = *(const float4*)(sc + h0);
    float4 biv = *(const float4*)(bi + h0);
    float hn0 = (xv.x - mu) * rs * scv.x + biv.x;
    float hn1 = (xv.y - mu) * rs * scv.y + biv.y;
    float hn2 = (xv.z - mu) * rs * scv.z + biv.z;
    float hn3 = (xv.w - mu) * rs * scv.w + biv.w;
    ushort4 o4; o4.x = f2bf(hn0); o4.y = f2bf(hn1); o4.z = f2bf(hn2); o4.w = f2bf(hn3);
    *(ushort4*)(Hbf + (size_t)row * ldh + h0) = o4;
    if (LORA) {
        int t = m_idx[row / (J_ * T_)];
        const float* Ap = lA + (size_t)t * (H_ * RANK_) + h0 * RANK_;
        float4 av[8];
        #pragma unroll
        for (int c = 0; c < 8; ++c) av[c] = ((const float4*)Ap)[c];
        float hn[4] = {hn0, hn1, hn2, hn3};
        float p[RANK_];
        #pragma unroll
        for (int k = 0; k < RANK_; ++k) p[k] = 0.f;
        #pragma unroll
        for (int i = 0; i < 4; ++i)
            #pragma unroll
            for (int k = 0; k < RANK_; ++k) {
                int idx = i * RANK_ + k;
                float a = (idx & 3) == 0 ? av[idx >> 2].x : (idx & 3) == 1 ? av[idx >> 2].y
                        : (idx & 3) == 2 ? av[idx >> 2].z : av[idx >> 2].w;
                p[k] += hn[i] * a;
            }
        #pragma unroll
        for (int k = 0; k < RANK_; ++k)
            #pragma unroll
            for (int o = 32; o; o >>= 1) p[k] += __shfl_xor(p[k], o);
        unsigned int w0 = (unsigned int)f2bf(p[0]) | ((unsigned int)f2bf(p[1]) << 16);
        unsigned int w1 = (unsigned int)f2bf(p[2]) | ((unsigned int)f2bf(p[3]) << 16);
        unsigned int w2 = (unsigned int)f2bf(p[4]) | ((unsigned int)f2bf(p[5]) << 16);
        unsigned int w3 = (unsigned int)f2bf(p[6]) | ((unsigned int)f2bf(p[7]) << 16);
        unsigned int tv = 0;
        if (lane == 0) tv = w0; else if (lane == 1) tv = w1;
        else if (lane == 2) tv = w2; else if (lane == 3) tv = w3;
        if (lane < 32)
            *((unsigned int*)(Hbf + (size_t)row * ldh + 256) + lane) = tv;
    }
}

// ---------------------------------------------------------------- final LayerNorm (in place, wave per row)
__global__ __launch_bounds__(256) void lnf_kernel(
    float* __restrict__ X, const float* __restrict__ sc, const float* __restrict__ bi) {
    int row = (blockIdx.x << 2) + (threadIdx.x >> 6);
    int lane = threadIdx.x & 63;
    int h0 = lane << 2;
    float4 xv = *(const float4*)(X + ((size_t)row << 8) + h0);
    float s1 = xv.x + xv.y + xv.z + xv.w;
    float s2 = xv.x * xv.x + xv.y * xv.y + xv.z * xv.z + xv.w * xv.w;
    #pragma unroll
    for (int o = 32; o; o >>= 1) { s1 += __shfl_xor(s1, o); s2 += __shfl_xor(s2, o); }
    float mu = s1 * (1.f / H_);
    float var = s2 * (1.f / H_) - mu * mu;
    float rs = rsqrtf(var + 1e-5f);
    float4 scv = *(const float4*)(sc + h0);
    float4 biv = *(const float4*)(bi + h0);
    float4 out;
    out.x = (xv.x - mu) * rs * scv.x + biv.x;
    out.y = (xv.y - mu) * rs * scv.y + biv.y;
    out.z = (xv.z - mu) * rs * scv.z + biv.z;
    out.w = (xv.w - mu) * rs * scv.w + biv.w;
    *(float4*)(X + ((size_t)row << 8) + h0) = out;
}

// ---------------------------------------------------------------- GEMM: C = A[ROWSxK] @ B[KxNc] (+epilogue)
// BK=32 double-buffered 2-phase pipeline with counted vmcnt (T3+T4) and
// both-sides XOR bank swizzle (rule #21: linear LDS dest + inverse-swizzled
// global source + swizzled ds_read).
// EPI 0: QKV  (bias, store bf16 ld=768; BT indexed by block-uniform model type)
// EPI 1: GELU (bias + gelu, store bf16 ld=Nc)
// EPI 2: RESID(bias, X += g*val, f32 ld=256)
template<int EPI>
__global__ __launch_bounds__(256) void gemm_k(
    const unsigned short* __restrict__ A, const unsigned short* __restrict__ BT,
    const float* __restrict__ bias,
    const float* __restrict__ aux1,   // RESID: gvec
    const int* __restrict__ m_idx,
    unsigned short* __restrict__ outB, float* __restrict__ outF,
    int K, int Nc) {
    __shared__ __align__(16) char LA[2][8192];   // 128 rows x 64B, double-buffered
    __shared__ __align__(16) char LB[2][8192];
    int gx = gridDim.x;
    int nwg = gx * gridDim.y;
    int id = blockIdx.y * gx + blockIdx.x;
    int bx = blockIdx.x, by = blockIdx.y;
    if ((nwg & 7) == 0) {
        int q8 = nwg >> 3;
        int sid = (id & 7) * q8 + (id >> 3);
        bx = sid % gx; by = sid / gx;
    }
    int col0 = bx * 128;
    int row0 = by * 128;
    int tid = threadIdx.x;
    int wv = tid >> 6, lane = tid & 63;
    int wm = wv >> 1, wn = wv & 1;

    if (EPI == 0) BT += (size_t)m_idx[row0 / (J_ * T_)] * (768 * KQ);

    // staging constants: thread stages 16B of row srow (4 threads/row, 64B rows)
    int srow  = tid >> 2;                       // 0..63 (it adds 64)
    int sbyte = (tid & 3) << 4;                 // 16B slot within row
    int sce   = (sbyte ^ SWZ(srow)) >> 1;       // inverse-swizzled global elem offset
    const unsigned short* Ab = A  + (size_t)(row0 + srow) * K + sce;
    const unsigned short* Bb = BT + (size_t)(col0 + srow) * K + sce;
    char* la0 = &LA[0][0] + tid * 16;           // it=0 dest; it=1 at +4096
    char* lb0 = &LB[0][0] + tid * 16;
    size_t rstep = (size_t)64 * K;              // it=1 global row offset

    // ds_read constants: per-lane swizzle is uniform across q (rows differ by 16)
    int ko2   = (lane >> 4) << 4;               // 16B k-slot (k = (lane>>4)*8)
    int rswz  = SWZ(lane & 15);
    int rdoff = ko2 ^ rswz;                     // byte offset within 64B row
    int rowA0 = wm * 64 + (lane & 15);
    int rowB0 = wn * 64 + (lane & 15);

    f32x4 acc[4][4];
    const f32x4 z = {0.f, 0.f, 0.f, 0.f};
    #pragma unroll
    for (int mi = 0; mi < 4; ++mi)
        #pragma unroll
        for (int ni = 0; ni < 4; ++ni) acc[mi][ni] = z;

    const int nt = K >> 5;                      // BK=32 tiles

    // prologue: stage tile 0 into buffer 0
    gload16(Ab,             la0);
    gload16(Ab + rstep,     la0 + 4096);
    gload16(Bb,             lb0);
    gload16(Bb + rstep,     lb0 + 4096);

    int cur = 0;
    for (int t = 0; t < nt; ++t) {
        int k0n = (t + 1) << 5;
        if (t + 1 < nt) {
            // issue next tile's loads into the other buffer (stay in flight)
            char* lan = &LA[cur ^ 1][0] + tid * 16;
            char* lbn = &LB[cur ^ 1][0] + tid * 16;
            gload16(Ab + k0n,         lan);
            gload16(Ab + rstep + k0n, lan + 4096);
            gload16(Bb + k0n,         lbn);
            gload16(Bb + rstep + k0n, lbn + 4096);
            asm volatile("s_waitcnt vmcnt(4)" ::: "memory");  // tile t resident; t+1 in flight
        } else {
            asm volatile("s_waitcnt vmcnt(0)" ::: "memory");
        }
        __builtin_amdgcn_s_barrier();
        __builtin_amdgcn_sched_barrier(0);

        const char* pa = &LA[cur][0];
        const char* pb = &LB[cur][0];
        short8 af[4], bfr[4];
        #pragma unroll
        for (int q = 0; q < 4; ++q) {
            af[q]  = *(const short8*)(pa + (rowA0 + q * 16) * 64 + rdoff);
            bfr[q] = *(const short8*)(pb + (rowB0 + q * 16) * 64 + rdoff);
        }
        #pragma unroll
        for (int mi = 0; mi < 4; ++mi)
            #pragma unroll
            for (int ni = 0; ni < 4; ++ni)
                acc[mi][ni] = __builtin_amdgcn_mfma_f32_16x16x32_bf16(af[mi], bfr[ni], acc[mi][ni], 0, 0, 0);

        __builtin_amdgcn_sched_barrier(0);
        __builtin_amdgcn_s_barrier();           // all reads of buf[cur] done before overwrite
        cur ^= 1;
    }

    int rbase = row0 + wm * 64 + ((lane >> 4) << 2);
    int cbase = col0 + wn * 64 + (lane & 15);

    if (EPI == 0 || EPI == 1) {
        const int ld = (EPI == 0) ? 768 : Nc;
        #pragma unroll
        for (int ni = 0; ni < 4; ++ni) {
            float bv = bias[cbase + ni * 16];
            #pragma unroll
            for (int mi = 0; mi < 4; ++mi)
                #pragma unroll
                for (int r = 0; r < 4; ++r) {
                    float u = acc[mi][ni][r] + bv;
                    if (EPI == 1) {
                        float tt = u * u;
                        float pp = fmaf(tt, 0.044715f, 1.0f) * u;
                        float e = __expf(-1.5957691216057308f * pp);
                        u = u / (1.f + e);
                    }
                    outB[(size_t)(rbase + mi * 16 + r) * ld + cbase + ni * 16] = f2bf(u);
                }
        }
    } else {
        #pragma unroll
        for (int mi = 0; mi < 4; ++mi)
            #pragma unroll
            for (int r = 0; r < 4; ++r) {
                int row = rbase + mi * 16 + r;
                #pragma unroll
                for (int ni = 0; ni < 4; ++ni) {
                    int col = cbase + ni * 16;
                    float u = acc[mi][ni][r] + bias[col];
                    outF[(size_t)row * H_ + col] += aux1[col] * u;
                }
            }
    }
}

// ---------------------------------------------------------------- attention: 4 waves = 4 heads, no syncthreads
__global__ __launch_bounds__(256) void attn_kernel(
    const unsigned short* __restrict__ QKV, const int* __restrict__ m_idx,
    unsigned short* __restrict__ O) {
    __shared__ unsigned int q2s[4][24][18];
    __shared__ unsigned int k2s[4][16][26];
    __shared__ unsigned int v2s[4][24][18];
    __shared__ float       scs[4][24][27];
    int w = threadIdx.x >> 6, lane = threadIdx.x & 63;
    int n = blockIdx.x >> 1;
    int hd = ((blockIdx.x & 1) << 2) + w;
    int nj = cNJ[m_idx[n >> 7]];
    unsigned int (*q2)[18] = q2s[w];
    unsigned int (*k2)[26] = k2s[w];
    unsigned int (*v2)[18] = v2s[w];
    float (*sc)[27] = scs[w];

    const unsigned short* base = QKV + (size_t)n * (J_ * 768) + hd * DH_;

    #pragma unroll
    for (int it = 0; it < 3; ++it) {
        int r = it * 64 + lane;
        int j = r >> 3, d0 = (r & 7) << 2, d2 = d0 >> 1;
        ushort4 x = *(const ushort4*)(base + (size_t)j * 768 + d0);
        q2[j][d2]     = (unsigned int)x.x | ((unsigned int)x.y << 16);
        q2[j][d2 + 1] = (unsigned int)x.z | ((unsigned int)x.w << 16);
    }
    #pragma unroll
    for (int it = 0; it < 3; ++it) {
        int r = it * 64 + lane;
        int j = r >> 3, d0 = (r & 7) << 2, d2 = d0 >> 1;
        ushort4 x = *(const ushort4*)(base + (size_t)j * 768 + 256 + d0);
        k2[d2][j]     = (unsigned int)x.x | ((unsigned int)x.y << 16);
        k2[d2 + 1][j] = (unsigned int)x.z | ((unsigned int)x.w << 16);
    }
    #pragma unroll
    for (int it = 0; it < 3; ++it) {
        int r = it * 64 + lane;
        int j = r >> 3, d0 = (r & 7) << 2, d2 = d0 >> 1;
        ushort4 x = *(const ushort4*)(base + (size_t)j * 768 + 512 + d0);
        v2[j][d2]     = (unsigned int)x.x | ((unsigned int)x.y << 16);
        v2[j][d2 + 1] = (unsigned int)x.z | ((unsigned int)x.w << 16);
    }

    int i = lane >> 1, half = lane & 1;
    if (lane < 48) {
        float qf[32];
        #pragma unroll
        for (int d2 = 0; d2 < 16; ++d2) {
            unsigned int x = q2[i][d2];
            qf[2 * d2]     = asf(x << 16);
            qf[2 * d2 + 1] = asf(x & 0xffff0000u);
        }
        int jb = half * 12;
        float s[12];
        #pragma unroll
        for (int jj = 0; jj < 12; ++jj) {
            int j = jb + jj;
            float acc = 0.f;
            #pragma unroll
            for (int d2 = 0; d2 < 16; ++d2) {
                unsigned int x = k2[d2][j];
                acc += qf[2 * d2] * asf(x << 16);
                acc += qf[2 * d2 + 1] * asf(x & 0xffff0000u);
            }
            bool ok = (i < nj && j < nj) || (i == j);
            s[jj] = ok ? acc * 0.17677669529663687f : -1e30f;
        }
        float mx = s[0];
        #pragma unroll
        for (int jj = 1; jj < 12; ++jj) mx = fmaxf(mx, s[jj]);
        mx = fmaxf(mx, __shfl_xor(mx, 1));
        float sm = 0.f;
        #pragma unroll
        for (int jj = 0; jj < 12; ++jj) { float e = __expf(s[jj] - mx); s[jj] = e; sm += e; }
        sm += __shfl_xor(sm, 1);
        float inv = 1.f / sm;
        #pragma unroll
        for (int jj = 0; jj < 12; ++jj) sc[i][jb + jj] = s[jj] * inv;
    }

    #pragma unroll
    for (int it = 0; it < 6; ++it) {
        int i2 = it * 4 + (lane >> 4), d2 = lane & 15;
        float olo = 0.f, ohi = 0.f;
        #pragma unroll
        for (int j = 0; j < J_; ++j) {
            float p = sc[i2][j];
            unsigned int x = v2[j][d2];
            olo += p * asf(x << 16);
            ohi += p * asf(x & 0xffff0000u);
        }
        unsigned int o = (unsigned int)f2bf(olo) | ((unsigned int)f2bf(ohi) << 16);
        *(unsigned int*)(O + (size_t)(n * J_ + i2) * H_ + hd * DH_ + 2 * d2) = o;
    }
}

// ---------------------------------------------------------------- host
extern "C" void kernel_launch(void* const* d_in, const int* in_sizes, int n_in,
                              void* d_out, int out_size, void* d_ws, size_t ws_size,
                              hipStream_t stream) {
    (void)in_sizes; (void)n_in; (void)out_size; (void)ws_size;
    const float* act   = (const float*)d_in[0];
    const void*  slide = d_in[1];
    const void*  hinge = d_in[2];
    const void*  glob  = d_in[3];
    const int* m_idx  = (const int*)d_in[6];
    const float* Ws   = (const float*)d_in[7];
    const float* bs   = (const float*)d_in[8];
    const float* Wh   = (const float*)d_in[9];
    const float* bh   = (const float*)d_in[10];
    const float* Wg   = (const float*)d_in[11];
    const float* Wact = (const float*)d_in[12];
    const float* pos  = (const float*)d_in[13];
    const float* ln1s = (const float*)d_in[14];
    const float* ln1b = (const float*)d_in[15];
    const float* Wqkv = (const float*)d_in[16];
    const float* bqkv = (const float*)d_in[17];
    const float* loraA= (const float*)d_in[18];
    const float* loraB= (const float*)d_in[19];
    const float* Wo   = (const float*)d_in[20];
    const float* bo   = (const float*)d_in[21];
    const float* ln2s = (const float*)d_in[22];
    const float* ln2b = (const float*)d_in[23];
    const float* W1   = (const float*)d_in[24];
    const float* b1   = (const float*)d_in[25];
    const float* W2   = (const float*)d_in[26];
    const float* b2   = (const float*)d_in[27];
    const float* g1   = (const float*)d_in[28];
    const float* g2   = (const float*)d_in[29];
    const float* lnfs = (const float*)d_in[30];
    const float* lnfb = (const float*)d_in[31];

    float* X = (float*)d_out;

    size_t off = 0;
    char* ws = (char*)d_ws;
    auto nxt = [&](size_t bytes) -> char* {
        char* p = ws + off; off += (bytes + 255) & ~(size_t)255; return p;
    };
    int*            dflag  = (int*)nxt(256);
    unsigned short* Hbf    = (unsigned short*)nxt((size_t)ROWS * KQ * 2);
    unsigned short* QKVG   = (unsigned short*)nxt((size_t)ROWS * 1024 * 2);
    unsigned short* WqkvTp = (unsigned short*)nxt((size_t)L_ * M_ * 768 * KQ * 2);
    unsigned short* WoT    = (unsigned short*)nxt((size_t)L_ * H_ * H_ * 2);
    unsigned short* W1T    = (unsigned short*)nxt((size_t)L_ * H_ * 1024 * 2);
    unsigned short* W2T    = (unsigned short*)nxt((size_t)L_ * 1024 * H_ * 2);
    unsigned short* Obf    = Hbf;   // lifetimes disjoint

    zero_flag<<<1, 1, 0, stream>>>(dflag);
    detect_kernel<<<(ROWS + 255) / 256, 256, 0, stream>>>(
        (const unsigned char*)slide, (const unsigned char*)hinge,
        (const unsigned char*)glob, m_idx, dflag);

    wconv_qkv<<<(L_ * M_ * 768 * KQ + 255) / 256, 256, 0, stream>>>(Wqkv, loraB, WqkvTp);
    wconv_t<<<(L_ * H_ * H_   + 255) / 256, 256, 0, stream>>>(Wo, WoT, H_, H_,   L_ * H_ * H_);
    wconv_t<<<(L_ * H_ * 1024 + 255) / 256, 256, 0, stream>>>(W1, W1T, H_, 1024, L_ * H_ * 1024);
    wconv_t<<<(L_ * 1024 * H_ + 255) / 256, 256, 0, stream>>>(W2, W2T, 1024, H_, L_ * 1024 * H_);

    embed_kernel<<<ROWS / 4, 256, 0, stream>>>(act, slide, hinge, glob, m_idx, dflag,
                                               Ws, bs, Wh, bh, Wg, Wact, pos, X);

    for (int l = 0; l < L_; ++l) {
        ln_kernel<true><<<ROWS / 4, 256, 0, stream>>>(X, ln1s + l * H_, ln1b + l * H_,
                                                      loraA + (size_t)l * M_ * H_ * RANK_, m_idx, Hbf, KQ);
        gemm_k<0><<<dim3(6, 384), 256, 0, stream>>>(Hbf, WqkvTp + (size_t)l * M_ * 768 * KQ,
                                                    bqkv + l * 768, nullptr, m_idx,
                                                    QKVG, nullptr, KQ, 768);
        attn_kernel<<<NTOK * 2, 256, 0, stream>>>(QKVG, m_idx, Obf);
        gemm_k<2><<<dim3(2, 384), 256, 0, stream>>>(Obf, WoT + (size_t)l * H_ * H_,
                                                    bo + l * H_, g1 + l * H_, m_idx,
                                                    nullptr, X, H_, H_);
        ln_kernel<false><<<ROWS / 4, 256, 0, stream>>>(X, ln2s + l * H_, ln2b + l * H_,
                                                       nullptr, nullptr, Hbf, H_);
        gemm_k<1><<<dim3(8, 384), 256, 0, stream>>>(Hbf, W1T + (size_t)l * H_ * 1024,
                                                    b1 + l * 1024, nullptr, m_idx,
                                                    QKVG, nullptr, H_, 1024);
        gemm_k<2><<<dim3(2, 384), 256, 0, stream>>>(QKVG, W2T + (size_t)l * 1024 * H_,
                                                    b2 + l * H_, g2 + l * H_, m_idx,
                                                    nullptr, X, 1024, H_);
    }

    lnf_kernel<<<ROWS / 4, 256, 0, stream>>>(X, lnfs, lnfb);
}